// Round 9
// baseline (7907.510 us; speedup 1.0000x reference)
//
#include <hip/hip_runtime.h>

// RecurrentGaussianActor: fused LSTM(64->256) + Linear+ReLU(256) + 2 heads(16).
// One WG per batch row, 256 WGs x 256 THREADS (4 waves, 1 wave/SIMD).
//
// Round-9 finding: VGPR pool = 512/SIMD (m69) -> at 2 waves/SIMD the wave
// budget is 256 unified regs. That single number explains every spill this
// session (r1/r2: 384 wanted vs 128; r7: 256+work vs 256; r8: 192+70 vs 256
// -> the 6.4GB FETCH reload). Fix: 256-thread blocks = 1 wave/SIMD = 512-reg
// budget. Same per-SIMD issue work and LDS traffic as the 512-thread shape.
//  * Thread u owns unit u COMPLETELY: 4 gate rows x 256 h. Weights: 96 h8 in
//    regs (384 = 75% of budget, the ratio r0 held cleanly at 192/256) +
//    32 h8 (slices 0..7) in LDS [col=g*8+s][tid], lane-linear b128.
//  * No DPP butterfly, no pair-replicated gate math, solo c_state.
//  * xg is THREAD-PRIVATE (rows g*256+u are unit u's own gates): computed
//    into private xg_l slots, zero barriers around the xg phase; wih_t/w2t/
//    wmt transposed in prep (r2-verified) for coalescing.
//  * Step loop: r8's proven issue-ahead pipeline, deepened (hv 4-deep
//    rotation, LDS-w double-buffer, all w-reads via wlA/wlB + imm offsets).
//  * 1 barrier/step; dbuf hbuf; obs staging and layer2/heads as before.
// Tells: FETCH >= 1.5 GB = allocator lost 384 regs (fallback: r8+trim);
// LDS_Block_Size ~158KB; VGPR_Count ~256 expected; Occupancy ~12 = by design.

#define NB 256
#define NT 1000
#define NF 64
#define NH 256
#define NG 1024
#define NA 16
#define NTHREADS 256
#define CHUNK 8
#define NCHUNK (NT / CHUNK)
#define SW 256  // whh_l column stride in h8

typedef _Float16 h2 __attribute__((ext_vector_type(2)));
typedef _Float16 h4 __attribute__((ext_vector_type(4)));
typedef _Float16 h8 __attribute__((ext_vector_type(8)));
typedef float f4 __attribute__((ext_vector_type(4)));

__device__ __forceinline__ float fdot2(h2 a, h2 b, float c) {
  return __builtin_amdgcn_fdot2(a, b, c, false);
}
__device__ __forceinline__ float fexp2(float x) { return __builtin_amdgcn_exp2f(x); }
__device__ __forceinline__ float frcp(float x) { return __builtin_amdgcn_rcpf(x); }
__device__ __forceinline__ float sigmoidf_(float x) {
  return frcp(1.f + fexp2(-1.4426950408889634f * x));
}
__device__ __forceinline__ float tanhfast(float x) {
  float a = fabsf(x);
  float e = fexp2(-2.8853900817779268f * a);
  float r = (1.f - e) * frcp(1.f + e);
  return __builtin_copysignf(r, x);
}
// dot of 8 f16 elements held in two h8 vectors (4 chained v_dot2_f32_f16)
__device__ __forceinline__ float dot8(h8 x, h8 w, float acc) {
  acc = fdot2(__builtin_shufflevector(x, x, 0, 1), __builtin_shufflevector(w, w, 0, 1), acc);
  acc = fdot2(__builtin_shufflevector(x, x, 2, 3), __builtin_shufflevector(w, w, 2, 3), acc);
  acc = fdot2(__builtin_shufflevector(x, x, 4, 5), __builtin_shufflevector(w, w, 4, 5), acc);
  acc = fdot2(__builtin_shufflevector(x, x, 6, 7), __builtin_shufflevector(w, w, 6, 7), acc);
  return acc;
}

// ---- prep: whh pairs + TRANSPOSED wih_t/w2t/wmt (r2-verified) + bg ----
// wih_t: h8 of row r, chunk j at &wih_t[j*4096 + r*4]   (h2 units)
// w2t  : h8 of row o, chunk c at &w2t[c*1024 + o*4]
// wmt  : h8 of row j, chunk c at &wmt[c*128 + j*4]      (rows: Wm 0..15, Ws 16..31)
__global__ void prep_kernel(const float* __restrict__ Wih, const float* __restrict__ Whh,
                            const float* __restrict__ bih, const float* __restrict__ bhh,
                            const float* __restrict__ W2, const float* __restrict__ Wm,
                            const float* __restrict__ Ws,
                            h2* __restrict__ whh, h2* __restrict__ wih_t,
                            h2* __restrict__ w2t, h2* __restrict__ wmt,
                            float* __restrict__ bg) {
  int i = blockIdx.x * 256 + threadIdx.x;
  if (i < 1024 * 128) {  // W_hh [1024][256] -> [1024][128] pairs
    int j = i >> 7, p = i & 127;
    whh[i] = h2{(_Float16)Whh[j * 256 + 2 * p], (_Float16)Whh[j * 256 + 2 * p + 1]};
  }
  if (i < 1024 * 32) {   // W_ih row r, pair p -> wih_t[(p>>2)*4096 + r*4 + (p&3)]
    int r = i >> 5, p = i & 31;
    wih_t[(p >> 2) * 4096 + r * 4 + (p & 3)] =
        h2{(_Float16)Wih[r * 64 + 2 * p], (_Float16)Wih[r * 64 + 2 * p + 1]};
  }
  if (i < 256 * 128) {   // W2 row o, pair p -> w2t[(p>>2)*1024 + o*4 + (p&3)]
    int o = i >> 7, p = i & 127;
    w2t[(p >> 2) * 1024 + o * 4 + (p & 3)] =
        h2{(_Float16)W2[o * 256 + 2 * p], (_Float16)W2[o * 256 + 2 * p + 1]};
  }
  if (i < 32 * 128) {    // Wm rows 0..15, Ws rows 16..31
    int j = i >> 7, p = i & 127;
    float v0, v1;
    if (j < 16) { v0 = Wm[j * 256 + 2 * p]; v1 = Wm[j * 256 + 2 * p + 1]; }
    else        { v0 = Ws[(j - 16) * 256 + 2 * p]; v1 = Ws[(j - 16) * 256 + 2 * p + 1]; }
    wmt[(p >> 2) * 128 + j * 4 + (p & 3)] = h2{(_Float16)v0, (_Float16)v1};
  }
  if (i < 1024) bg[i] = bih[i] + bhh[i];
}

// 4-gate dot cluster against wreg column j (reg-weight phase)
#define DOT4R(hv, j)                  \
  p0 = dot8(hv, wreg[j], p0);         \
  p1 = dot8(hv, wreg[24 + (j)], p1);  \
  p2 = dot8(hv, wreg[48 + (j)], p2);  \
  p3 = dot8(hv, wreg[72 + (j)], p3);
// 4-gate dot cluster against the u*/v* LDS-weight double buffers
#define DOT4U(hv)                                                      \
  p0 = dot8(hv, u0, p0); p1 = dot8(hv, u1, p1);                        \
  p2 = dot8(hv, u2, p2); p3 = dot8(hv, u3, p3);
#define DOT4V(hv)                                                      \
  p0 = dot8(hv, v0, p0); p1 = dot8(hv, v1, p1);                        \
  p2 = dot8(hv, v2, p2); p3 = dot8(hv, v3, p3);

// ---- main fused persistent kernel: 1 WG per batch row ----
__global__ __launch_bounds__(NTHREADS, 1)
__attribute__((amdgpu_waves_per_eu(1, 1))) void actor_kernel(
    const float* __restrict__ obs,
    const h2* __restrict__ whh, const h2* __restrict__ wih_t,
    const h2* __restrict__ w2t, const h2* __restrict__ wmt,
    const float* __restrict__ bg, const float* __restrict__ b2,
    const float* __restrict__ bm, const float* __restrict__ bs,
    float* __restrict__ out) {
  __shared__ __align__(16) h8 whh_l[32 * NTHREADS];     // 131072 B [g*8+s][tid]
  __shared__ __align__(16) _Float16 xg_l[CHUNK * NG];   // 16384 B  [t][u][4g] private
  __shared__ __align__(16) h2 hbuf[2][NH / 2];          // 1024 B   dbuf h
  __shared__ __align__(16) h2 hch[CHUNK][NH / 2];       // 4096 B   h history
  __shared__ __align__(16) h2 xbuf[CHUNK][NF / 2];      // 1024 B   obs chunk
  __shared__ __align__(16) h2 x2b[CHUNK][NH / 2];       // 4096 B   layer2 out
  // total 157696 B <= 163840

  const int un = threadIdx.x;   // unit owned by this thread
  const int b = blockIdx.x;

  // ---- register-resident W_hh: h8 slices 8..31 of unit un's 4 gate rows ----
  // 96 x h8 = 384 regs (75% of the 512-reg 1-wave/SIMD budget -- same ratio
  // r0 held cleanly at 192/256). VOLATILE: no remat inside the step loop.
  h8 wreg[96];
  {
    const volatile h8* vw = (const volatile h8*)whh;  // row stride = 32 h8
#pragma unroll
    for (int g = 0; g < 4; g++)
#pragma unroll
      for (int j = 0; j < 24; j++)
        wreg[g * 24 + j] = vw[(g * 256 + un) * 32 + 8 + j];
  }
  // ---- LDS-resident W_hh: h8 slices 0..7, column (g*8+s), index tid ----
  {
    const h8* whh8 = (const h8*)whh;
#pragma unroll
    for (int g = 0; g < 4; g++)
#pragma unroll
      for (int s = 0; s < 8; s++)
        whh_l[(g * 8 + s) * NTHREADS + un] = whh8[(g * 256 + un) * 32 + s];
  }
  if (un < NH / 2) hbuf[0][un] = h2{(_Float16)0.f, (_Float16)0.f};
  float c_state = 0.f;  // solo-owned: no replication, no butterfly
  const float bgv0 = bg[un], bgv1 = bg[256 + un];
  const float bgv2 = bg[512 + un], bgv3 = bg[768 + un];
  const float b2v = b2[un];
  const int oh = un & 31, th = un >> 5;  // heads: (output, timestep)
  const float hbv = (oh < NA) ? bm[oh] : bs[oh - NA];
  __syncthreads();

  const float* obs_b = obs + (size_t)b * NT * NF;
  float* out_means = out;
  float* out_stds = out + (size_t)NB * NT * NA;
  const h8* wlA = whh_l + un;                  // cols 0..15  (gates 0,1)
  const h8* wlB = whh_l + 16 * NTHREADS + un;  // cols 16..31 (gates 2,3)

  for (int ch = 0; ch < NCHUNK; ++ch) {
    const int t0 = ch * CHUNK;

    // ---- stage obs chunk -> f16 pairs in LDS ----
    if (un < 128) {
      int tq = un >> 4, fq = un & 15;
      f4 v = *(const f4*)(obs_b + (size_t)(t0 + tq) * NF + fq * 4);
      xbuf[tq][fq * 2] = h2{(_Float16)v[0], (_Float16)v[1]};
      xbuf[tq][fq * 2 + 1] = h2{(_Float16)v[2], (_Float16)v[3]};
    }
    __syncthreads();

    // ---- xg: unit un's OWN 4 gate rows x 8 t; private slots, no barrier ----
#pragma unroll
    for (int g = 0; g < 4; g++) {
      const float bias = (g == 0) ? bgv0 : (g == 1) ? bgv1 : (g == 2) ? bgv2 : bgv3;
      float acc[CHUNK];
#pragma unroll
      for (int tq = 0; tq < CHUNK; tq++) acc[tq] = bias;
#pragma unroll
      for (int j = 0; j < 8; j++) {
        h8 w = *(const h8*)&wih_t[(size_t)j * 4096 + (g * 256 + un) * 4];
#pragma unroll
        for (int tq = 0; tq < CHUNK; tq++)
          acc[tq] = dot8(*(const h8*)&xbuf[tq][j * 4], w, acc[tq]);
      }
#pragma unroll
      for (int tq = 0; tq < CHUNK; tq++)
        xg_l[(tq * 256 + un) * 4 + g] = (_Float16)acc[tq];
    }

    // ---- 8 recurrent LSTM steps, ONE barrier each; pipelined (r8 pattern) ----
    for (int t = 0; t < CHUNK; t++) {
      const h8* hb8 = (const h8*)&hbuf[t & 1][0];  // wave-uniform broadcasts
      h4 xg4 = *(const h4*)&xg_l[(t * 256 + un) * 4];
      float p0 = 0.f, p1 = 0.f, p2 = 0.f, p3 = 0.f;
      // prefetch hv group A + w(s=0)
      h8 a0 = hb8[0], a1 = hb8[1], a2 = hb8[2], a3 = hb8[3];
      h8 u0 = wlA[0 * SW], u1 = wlA[8 * SW], u2 = wlB[0 * SW], u3 = wlB[8 * SW];
      h8 v0, v1, v2, v3, b0, b1, b2, b3;
      // s=0: issue w(s=1); consume a0 x u
      v0 = wlA[1 * SW]; v1 = wlA[9 * SW]; v2 = wlB[1 * SW]; v3 = wlB[9 * SW];
      DOT4U(a0)
      // s=1: issue w(s=2); consume a1 x v
      u0 = wlA[2 * SW]; u1 = wlA[10 * SW]; u2 = wlB[2 * SW]; u3 = wlB[10 * SW];
      DOT4V(a1)
      // s=2: issue w(s=3); consume a2 x u
      v0 = wlA[3 * SW]; v1 = wlA[11 * SW]; v2 = wlB[3 * SW]; v3 = wlB[11 * SW];
      DOT4U(a2)
      // s=3: issue hv B + w(s=4); consume a3 x v
      b0 = hb8[4]; b1 = hb8[5]; b2 = hb8[6]; b3 = hb8[7];
      u0 = wlA[4 * SW]; u1 = wlA[12 * SW]; u2 = wlB[4 * SW]; u3 = wlB[12 * SW];
      DOT4V(a3)
      // s=4: issue w(s=5); consume b0 x u
      v0 = wlA[5 * SW]; v1 = wlA[13 * SW]; v2 = wlB[5 * SW]; v3 = wlB[13 * SW];
      DOT4U(b0)
      // s=5: issue w(s=6); consume b1 x v
      u0 = wlA[6 * SW]; u1 = wlA[14 * SW]; u2 = wlB[6 * SW]; u3 = wlB[14 * SW];
      DOT4V(b1)
      // s=6: issue hv A (8..11) + w(s=7); consume b2 x u
      a0 = hb8[8]; a1 = hb8[9]; a2 = hb8[10]; a3 = hb8[11];
      v0 = wlA[7 * SW]; v1 = wlA[15 * SW]; v2 = wlB[7 * SW]; v3 = wlB[15 * SW];
      DOT4U(b2)
      // s=7: consume b3 x v; then issue hv B (12..15)
      DOT4V(b3)
      b0 = hb8[12]; b1 = hb8[13]; b2 = hb8[14]; b3 = hb8[15];
      // ---- reg-weight phase: 24 hv clusters, refill at distance 4 ----
      DOT4R(a0, 0)  a0 = hb8[16];
      DOT4R(a1, 1)  a1 = hb8[17];
      DOT4R(a2, 2)  a2 = hb8[18];
      DOT4R(a3, 3)  a3 = hb8[19];
      DOT4R(b0, 4)  b0 = hb8[20];
      DOT4R(b1, 5)  b1 = hb8[21];
      DOT4R(b2, 6)  b2 = hb8[22];
      DOT4R(b3, 7)  b3 = hb8[23];
      DOT4R(a0, 8)  a0 = hb8[24];
      DOT4R(a1, 9)  a1 = hb8[25];
      DOT4R(a2, 10) a2 = hb8[26];
      DOT4R(a3, 11) a3 = hb8[27];
      DOT4R(b0, 12) b0 = hb8[28];
      DOT4R(b1, 13) b1 = hb8[29];
      DOT4R(b2, 14) b2 = hb8[30];
      DOT4R(b3, 15) b3 = hb8[31];
      DOT4R(a0, 16) DOT4R(a1, 17) DOT4R(a2, 18) DOT4R(a3, 19)
      DOT4R(b0, 20) DOT4R(b1, 21) DOT4R(b2, 22) DOT4R(b3, 23)
      // ---- gates (solo, no exchange) ----
      float gi = sigmoidf_(p0 + (float)xg4[0]);
      float gf = sigmoidf_(p1 + (float)xg4[1]);
      float gg = tanhfast(p2 + (float)xg4[2]);
      float go = sigmoidf_(p3 + (float)xg4[3]);
      c_state = gf * c_state + gi * gg;
      float hval = go * tanhfast(c_state);
      _Float16 hh = (_Float16)hval;
      ((_Float16*)&hbuf[(t + 1) & 1][0])[un] = hh;  // publish h(t+1)
      ((_Float16*)&hch[t][0])[un] = hh;             // history for layer2
      __syncthreads();
    }

    // ---- layer2: x2 = relu(h @ W2^T + b2); o = tid, 8 timesteps ----
    {
      float acc[CHUNK];
#pragma unroll
      for (int tq = 0; tq < CHUNK; tq++) acc[tq] = b2v;
      h8 wa = *(const h8*)&w2t[(size_t)0 * 1024 + un * 4];
#pragma unroll
      for (int c = 0; c < 32; c++) {
        h8 wb = wa;
        if (c < 31) wb = *(const h8*)&w2t[(size_t)(c + 1) * 1024 + un * 4];
#pragma unroll
        for (int tq = 0; tq < CHUNK; tq++)
          acc[tq] = dot8(*(const h8*)&hch[tq][c * 4], wa, acc[tq]);
        wa = wb;
      }
#pragma unroll
      for (int tq = 0; tq < CHUNK; tq++)
        ((_Float16*)&x2b[tq][0])[un] = (_Float16)fmaxf(acc[tq], 0.f);
    }
    __syncthreads();

    // ---- heads: all 256 threads: (oh = un&31, th = un>>5) ----
    {
      float acc = 0.f;
#pragma unroll 4
      for (int c = 0; c < 32; c++) {
        h8 xv = *(const h8*)&x2b[th][c * 4];
        h8 w = *(const h8*)&wmt[(size_t)c * 128 + oh * 4];
        acc = dot8(xv, w, acc);
      }
      acc += hbv;
      const size_t idx = ((size_t)b * NT + (t0 + th)) * NA + (oh & 15);
      if (oh < NA) {
        out_means[idx] = acc;
      } else {
        float ls = fminf(fmaxf(acc, -20.f), 2.f);
        out_stds[idx] = fexp2(1.4426950408889634f * ls);
      }
    }
    // no trailing barrier: next chunk's x2b writes (its layer2) are separated
    // from these reads by the staging barrier + 8 step barriers; next stage
    // writes xbuf whose last readers (this chunk's xg) are long past.
  }
}

#undef DOT4R
#undef DOT4U
#undef DOT4V

extern "C" void kernel_launch(void* const* d_in, const int* in_sizes, int n_in,
                              void* d_out, int out_size, void* d_ws, size_t ws_size,
                              hipStream_t stream) {
  const float* obs = (const float*)d_in[0];
  const float* Wih = (const float*)d_in[1];
  const float* Whh = (const float*)d_in[2];
  const float* bih = (const float*)d_in[3];
  const float* bhh = (const float*)d_in[4];
  const float* W2 = (const float*)d_in[5];
  const float* b2 = (const float*)d_in[6];
  const float* Wm = (const float*)d_in[7];
  const float* bm = (const float*)d_in[8];
  const float* Ws = (const float*)d_in[9];
  const float* bs = (const float*)d_in[10];

  char* ws = (char*)d_ws;
  h2* whh = (h2*)(ws + 0);              // 512 KB
  h2* wih_t = (h2*)(ws + 524288);       // 128 KB
  h2* w2t = (h2*)(ws + 655360);         // 128 KB
  h2* wmt = (h2*)(ws + 786432);         // 16 KB
  float* bg = (float*)(ws + 802816);    // 4 KB

  prep_kernel<<<512, 256, 0, stream>>>(Wih, Whh, bih, bhh, W2, Wm, Ws,
                                       whh, wih_t, w2t, wmt, bg);
  actor_kernel<<<NB, NTHREADS, 0, stream>>>(obs, whh, wih_t, w2t, wmt, bg, b2,
                                            bm, bs, (float*)d_out);
}

// Round 10
// 4336.486 us; speedup vs baseline: 1.8235x; 1.8235x over previous
//
#include <hip/hip_runtime.h>

// RecurrentGaussianActor: fused LSTM(64->256) + Linear+ReLU(256) + 2 heads(16).
// One WG per batch row (256 WGs x 512 threads), persistent over T=1000 steps.
//
// Round-10: r8 (best, 4300us) re-scheduled to FIT THE 256-REG WAVE BUDGET.
// Ledger: allocator holds exactly 192 values in AGPR (r0/r4/r8; never more:
// r7/r9 proved 256/384 always spill) + arch temps must fit 256-wave budget at
// 2 waves/SIMD. r8's pipeline used ~90 arch temps -> 282 demand -> ~3 h8
// reloaded per step from scratch = 6.4 GB HBM FETCH. This round keeps r8's
// issue-ahead pipeline but halves its live set:
//  * hv group of 4 (a0-3) with distance-3 refills (~96 issue-cy lead), was 8.
//  * LDS-weight phase split by GATE PAIR: phase A (gates 0,1; p0,p1) then
//    phase B (gates 2,3; p2,p3) over s=0..3; w double-buffer is 2 regs/side
//    instead of 4 -> w-live 8 h8 -> 4 h8.
//  * everything else r8-verbatim: layer2 W2 double-buffer, heads, xg
//    [t][u][4g], volatile wreg[48], padded dbuf hbuf, 1 barrier/step.
// Demand ~= 192 AGPR + ~55 arch = ~247 <= 256.
// THE tell: FETCH < 1.5 GB = fit (expect ~0.6); FETCH >= 5 GB = failed, r8
// stands as the configuration of record.

#define NB 256
#define NT 1000
#define NF 64
#define NH 256
#define NG 1024
#define NA 16
#define NTHREADS 512
#define CHUNK 8
#define NCHUNK (NT / CHUNK)
#define HHALF 68  // h2 units per padded h-half: 128 f16 = 64 h2, +4 h2 pad = 272 B

typedef _Float16 h2 __attribute__((ext_vector_type(2)));
typedef _Float16 h4 __attribute__((ext_vector_type(4)));
typedef _Float16 h8 __attribute__((ext_vector_type(8)));
typedef float f4 __attribute__((ext_vector_type(4)));

__device__ __forceinline__ float fdot2(h2 a, h2 b, float c) {
  return __builtin_amdgcn_fdot2(a, b, c, false);
}
__device__ __forceinline__ float fexp2(float x) { return __builtin_amdgcn_exp2f(x); }
__device__ __forceinline__ float frcp(float x) { return __builtin_amdgcn_rcpf(x); }
__device__ __forceinline__ float sigmoidf_(float x) {
  return frcp(1.f + fexp2(-1.4426950408889634f * x));
}
__device__ __forceinline__ float tanhfast(float x) {
  float a = fabsf(x);
  float e = fexp2(-2.8853900817779268f * a);
  float r = (1.f - e) * frcp(1.f + e);
  return __builtin_copysignf(r, x);
}
// dot of 8 f16 elements held in two h8 vectors (4 chained v_dot2_f32_f16)
__device__ __forceinline__ float dot8(h8 x, h8 w, float acc) {
  acc = fdot2(__builtin_shufflevector(x, x, 0, 1), __builtin_shufflevector(w, w, 0, 1), acc);
  acc = fdot2(__builtin_shufflevector(x, x, 2, 3), __builtin_shufflevector(w, w, 2, 3), acc);
  acc = fdot2(__builtin_shufflevector(x, x, 4, 5), __builtin_shufflevector(w, w, 4, 5), acc);
  acc = fdot2(__builtin_shufflevector(x, x, 6, 7), __builtin_shufflevector(w, w, 6, 7), acc);
  return acc;
}
// quad_perm DPP: CTRL=0xB1 -> lanes (1,0,3,2) [xor1 within each quad]
template <int CTRL>
__device__ __forceinline__ float qperm(float x) {
  return __int_as_float(
      __builtin_amdgcn_update_dpp(0, __float_as_int(x), CTRL, 0xF, 0xF, true));
}

// ---- prep: convert/pack weights to f16 pairs in workspace (round-0 verbatim) ----
__global__ void prep_kernel(const float* __restrict__ Wih, const float* __restrict__ Whh,
                            const float* __restrict__ bih, const float* __restrict__ bhh,
                            const float* __restrict__ W2, const float* __restrict__ Wm,
                            const float* __restrict__ Ws,
                            h2* __restrict__ whh, h2* __restrict__ wih,
                            h2* __restrict__ w2w, h2* __restrict__ wmh,
                            float* __restrict__ bg) {
  int i = blockIdx.x * 256 + threadIdx.x;
  if (i < 1024 * 128) {  // W_hh [1024][256] -> [1024][128] pairs
    int j = i >> 7, p = i & 127;
    whh[i] = h2{(_Float16)Whh[j * 256 + 2 * p], (_Float16)Whh[j * 256 + 2 * p + 1]};
  }
  if (i < 1024 * 32) {   // W_ih [1024][64] -> [1024][32] pairs
    int j = i >> 5, p = i & 31;
    wih[i] = h2{(_Float16)Wih[j * 64 + 2 * p], (_Float16)Wih[j * 64 + 2 * p + 1]};
  }
  if (i < 256 * 128) {   // W2 [256][256] -> [256][128] pairs
    int j = i >> 7, p = i & 127;
    w2w[i] = h2{(_Float16)W2[j * 256 + 2 * p], (_Float16)W2[j * 256 + 2 * p + 1]};
  }
  if (i < 32 * 128) {    // Wm rows 0..15, Ws rows 16..31
    int j = i >> 7, p = i & 127;
    float v0, v1;
    if (j < 16) { v0 = Wm[j * 256 + 2 * p]; v1 = Wm[j * 256 + 2 * p + 1]; }
    else        { v0 = Ws[(j - 16) * 256 + 2 * p]; v1 = Ws[(j - 16) * 256 + 2 * p + 1]; }
    wmh[i] = h2{(_Float16)v0, (_Float16)v1};
  }
  if (i < 1024) bg[i] = bih[i] + bhh[i];
}

// 4-gate dot cluster against wreg column j (reg-weight phase)
#define DOT4R(hv, j)                  \
  p0 = dot8(hv, wreg[j], p0);         \
  p1 = dot8(hv, wreg[12 + (j)], p1);  \
  p2 = dot8(hv, wreg[24 + (j)], p2);  \
  p3 = dot8(hv, wreg[36 + (j)], p3);

// ---- main fused persistent kernel: 1 WG per batch row ----
__global__ __launch_bounds__(NTHREADS, 2) void actor_kernel(
    const float* __restrict__ obs,
    const h2* __restrict__ whh, const h2* __restrict__ wih,
    const h2* __restrict__ w2w, const h2* __restrict__ wmh,
    const float* __restrict__ bg, const float* __restrict__ b2,
    const float* __restrict__ bm, const float* __restrict__ bs,
    float* __restrict__ out) {
  // W_hh h8-slices 0..3 of this thread's (4 rows x own h-half): 16 columns
  // of [512] h8; reads lane-linear b128 -> conflict-free (r4/r8 layout).
  __shared__ __align__(16) h8 whh_l[16 * NTHREADS];        // 131072 B
  __shared__ __align__(16) _Float16 xg_l[CHUNK * NG];      // 16384 B [t][u][4g]
  __shared__ __align__(16) h2 hbuf[2][2 * HHALF];          // 1088 B padded dbuf h
  __shared__ __align__(16) h2 hch[CHUNK * NH / 2];         // 4096 B  h history
  __shared__ __align__(16) h2 xbuf[CHUNK * NF / 2];        // 1024 B  obs chunk
  __shared__ __align__(16) h2 x2b[CHUNK * NH / 2];         // 4096 B  layer2 out
  // total 157760 B <= 163840

  const int tid = threadIdx.x;
  const int b = blockIdx.x;
  const int q = tid >> 1;      // hidden unit owned by this lane pair
  const int jhalf = tid & 1;   // h-half [128*jhalf, 128*jhalf+128)

  // ---- register-resident W_hh: h8s 4..15 of own half, 4 gate rows of q ----
  // 48 x h8 = 192 regs: the allocator's proven AGPR capacity (r0/r4/r8);
  // r7/r9 proved anything larger spills. VOLATILE: no remat in step loop.
  h8 wreg[48];
  {
    const volatile h8* vw = (const volatile h8*)whh;  // row stride = 32 h8
#pragma unroll
    for (int g = 0; g < 4; g++)
#pragma unroll
      for (int jj = 0; jj < 12; jj++)
        wreg[g * 12 + jj] = vw[(g * 256 + q) * 32 + jhalf * 16 + 4 + jj];
  }
  // ---- LDS-resident W_hh: h8s 0..3 of own half, column (g*4+s), idx tid ----
  {
    const h8* whh8 = (const h8*)whh;
#pragma unroll
    for (int g = 0; g < 4; g++)
#pragma unroll
      for (int s = 0; s < 4; s++)
        whh_l[(g * 4 + s) * NTHREADS + tid] = whh8[(g * 256 + q) * 32 + jhalf * 16 + s];
  }
  if (tid < 2 * HHALF) hbuf[0][tid] = h2{(_Float16)0.f, (_Float16)0.f};
  float c_state = 0.f;  // replicated across the lane pair
  const float bg0 = bg[tid], bg1 = bg[tid + 512];  // xg bias rows tid, tid+512
  const float b2v = b2[tid & 255];
  const int oh = tid & 31;
  const float hbv = (oh < NA) ? bm[oh] : bs[oh - NA];
  __syncthreads();

  const float* obs_b = obs + (size_t)b * NT * NF;
  float* out_means = out;
  float* out_stds = out + (size_t)NB * NT * NA;
  // weight base pointers: all step-loop w-reads are ds_read with
  // compile-time offset: immediates.
  const h8* wlA = whh_l + tid;                 // gates 0,1: elem (g*4+s)*512
  const h8* wlB = whh_l + 8 * NTHREADS + tid;  // gates 2,3

  for (int ch = 0; ch < NCHUNK; ++ch) {
    const int t0 = ch * CHUNK;

    // ---- stage obs chunk -> f16 pairs in LDS (round-0 verbatim) ----
    if (tid < 128) {
      int t = tid >> 4, fq = tid & 15;
      f4 v = *(const f4*)(obs_b + (size_t)(t0 + t) * NF + fq * 4);
      xbuf[t * 32 + fq * 2] = h2{(_Float16)v[0], (_Float16)v[1]};
      xbuf[t * 32 + fq * 2 + 1] = h2{(_Float16)v[2], (_Float16)v[3]};
    }
    __syncthreads();

    // ---- xg for rows tid and tid+512 (round-0 math, [t][u][4g] store) ----
#pragma unroll
    for (int rr = 0; rr < 2; ++rr) {
      const int row = tid + rr * 512;
      const float bias = rr ? bg1 : bg0;
      float acc[CHUNK];
#pragma unroll
      for (int t = 0; t < CHUNK; t++) acc[t] = bias;
      const h8* wrow = (const h8*)wih + row * 8;
#pragma unroll
      for (int jh = 0; jh < 2; jh++) {
        h8 w[4];
#pragma unroll
        for (int qq = 0; qq < 4; qq++) w[qq] = wrow[jh * 4 + qq];
#pragma unroll
        for (int t = 0; t < CHUNK; t++) {
#pragma unroll
          for (int qq = 0; qq < 4; qq++) {
            h8 xv = *(const h8*)&xbuf[t * 32 + jh * 16 + qq * 4];
            acc[t] = dot8(xv, w[qq], acc[t]);
          }
        }
      }
      const int g = row >> 8, uu = row & 255;
#pragma unroll
      for (int t = 0; t < CHUNK; t++)
        xg_l[(t * 256 + uu) * 4 + g] = (_Float16)acc[t];
    }
    __syncthreads();

    // ---- 8 recurrent LSTM steps, ONE barrier each; trimmed pipeline ----
    // Live temps: a0-3 (4 h8) + u0,u1/v0,v1 (4 h8) + p0-3 + xg4 ~ 55 arch.
    for (int t = 0; t < CHUNK; t++) {
      const h8* hb8 =
          (const h8*)((const _Float16*)&hbuf[t & 1][jhalf * HHALF]);
      h4 xg4 = *(const h4*)&xg_l[(t * 256 + q) * 4];
      float p0 = 0.f, p1 = 0.f, p2 = 0.f, p3 = 0.f;
      // prefetch hv group (4) + first gate-pair w (gates 0,1; s=0)
      h8 a0 = hb8[0], a1 = hb8[1], a2 = hb8[2], a3 = hb8[3];
      h8 u0 = wlA[0 * NTHREADS], u1 = wlA[4 * NTHREADS];
      h8 v0, v1;
      // phase A: gates 0,1 over s=0..3 (w lead = 1 cluster)
      v0 = wlA[1 * NTHREADS]; v1 = wlA[5 * NTHREADS];
      p0 = dot8(a0, u0, p0); p1 = dot8(a0, u1, p1);
      u0 = wlA[2 * NTHREADS]; u1 = wlA[6 * NTHREADS];
      p0 = dot8(a1, v0, p0); p1 = dot8(a1, v1, p1);
      v0 = wlA[3 * NTHREADS]; v1 = wlA[7 * NTHREADS];
      p0 = dot8(a2, u0, p0); p1 = dot8(a2, u1, p1);
      u0 = wlB[0 * NTHREADS]; u1 = wlB[4 * NTHREADS];  // start phase B prefetch
      p0 = dot8(a3, v0, p0); p1 = dot8(a3, v1, p1);
      // phase B: gates 2,3 over s=0..3
      v0 = wlB[1 * NTHREADS]; v1 = wlB[5 * NTHREADS];
      p2 = dot8(a0, u0, p2); p3 = dot8(a0, u1, p3);
      u0 = wlB[2 * NTHREADS]; u1 = wlB[6 * NTHREADS];
      p2 = dot8(a1, v0, p2); p3 = dot8(a1, v1, p3);
      v0 = wlB[3 * NTHREADS]; v1 = wlB[7 * NTHREADS];
      p2 = dot8(a2, u0, p2); p3 = dot8(a2, u1, p3);
      a0 = hb8[4]; a1 = hb8[5];  // begin hv refills for the reg phase
      p2 = dot8(a3, v0, p2); p3 = dot8(a3, v1, p3);
      a2 = hb8[6]; a3 = hb8[7];
      // reg-weight phase: 12 clusters (hv j=4..15), refill at distance 3
      DOT4R(a0, 0)  a0 = hb8[8];
      DOT4R(a1, 1)  a1 = hb8[9];
      DOT4R(a2, 2)  a2 = hb8[10];
      DOT4R(a3, 3)  a3 = hb8[11];
      DOT4R(a0, 4)  a0 = hb8[12];
      DOT4R(a1, 5)  a1 = hb8[13];
      DOT4R(a2, 6)  a2 = hb8[14];
      DOT4R(a3, 7)  a3 = hb8[15];
      DOT4R(a0, 8)
      DOT4R(a1, 9)
      DOT4R(a2, 10)
      DOT4R(a3, 11)
      // xor-1 DPP butterfly: both lanes of the pair get all 4 full sums.
      p0 += qperm<0xB1>(p0);
      p1 += qperm<0xB1>(p1);
      p2 += qperm<0xB1>(p2);
      p3 += qperm<0xB1>(p3);
      float gi = sigmoidf_(p0 + (float)xg4[0]);
      float gf = sigmoidf_(p1 + (float)xg4[1]);
      float gg = tanhfast(p2 + (float)xg4[2]);
      float go = sigmoidf_(p3 + (float)xg4[3]);
      c_state = gf * c_state + gi * gg;
      float hval = go * tanhfast(c_state);
      if (jhalf == 0) {  // one lane per unit publishes
        _Float16 hh = (_Float16)hval;
        ((_Float16*)&hbuf[(t + 1) & 1][(q >> 7) * HHALF])[q & 127] = hh;
        ((_Float16*)hch)[t * NH + q] = hh;  // history for layer2
      }
      __syncthreads();  // h(t+1) visible; hbuf[t&1] free for step t+2's write
    }

    // ---- layer2: x2 = relu(h @ W2^T + b2); W2 row double-buffered (r8) ----
    {
      const int o = tid & 255;
      const int tb = (tid >> 8) * 4;  // 4 timesteps per thread
      float acc[4] = {b2v, b2v, b2v, b2v};
      const h8* wrow = (const h8*)w2w + o * 32;
      const h8* hs = (const h8*)hch + tb * 32;  // xv = hs[tt*32 + c*4 + qq]
      h8 wa[4], wb[4];
#pragma unroll
      for (int qq = 0; qq < 4; qq++) wa[qq] = wrow[qq];
#pragma unroll
      for (int cc = 0; cc < 4; cc++) {
        const int ce = 2 * cc, codd = 2 * cc + 1;
        const int cn = (2 * cc + 2 < 8) ? 2 * cc + 2 : 7;  // tail reread, harmless
#pragma unroll
        for (int qq = 0; qq < 4; qq++) wb[qq] = wrow[codd * 4 + qq];
#pragma unroll
        for (int tt = 0; tt < 4; tt++)
#pragma unroll
          for (int qq = 0; qq < 4; qq++)
            acc[tt] = dot8(hs[tt * 32 + ce * 4 + qq], wa[qq], acc[tt]);
#pragma unroll
        for (int qq = 0; qq < 4; qq++) wa[qq] = wrow[cn * 4 + qq];
#pragma unroll
        for (int tt = 0; tt < 4; tt++)
#pragma unroll
          for (int qq = 0; qq < 4; qq++)
            acc[tt] = dot8(hs[tt * 32 + codd * 4 + qq], wb[qq], acc[tt]);
      }
#pragma unroll
      for (int tt = 0; tt < 4; tt++)
        ((_Float16*)x2b)[(tb + tt) * NH + o] = (_Float16)fmaxf(acc[tt], 0.f);
    }
    __syncthreads();

    // ---- heads: 32 outputs x 8 timesteps on first 256 threads (verbatim) ----
    if (tid < 256) {
      const int tt = tid >> 5;
      const h8* wrow = (const h8*)wmh + oh * 32;
      float acc = 0.f;
#pragma unroll 4
      for (int c = 0; c < 32; c++) {
        h8 xv = *(const h8*)&x2b[tt * 128 + c * 4];
        acc = dot8(xv, wrow[c], acc);
      }
      acc += hbv;
      const size_t idx = ((size_t)b * NT + (t0 + tt)) * NA + (oh & 15);
      if (oh < NA) {
        out_means[idx] = acc;
      } else {
        float ls = fminf(fmaxf(acc, -20.f), 2.f);
        out_stds[idx] = fexp2(1.4426950408889634f * ls);
      }
    }
    // no trailing barrier: next chunk's first write to x2b (its layer2) is
    // separated from these reads by the staging/xg/step barriers.
  }
}

#undef DOT4R

extern "C" void kernel_launch(void* const* d_in, const int* in_sizes, int n_in,
                              void* d_out, int out_size, void* d_ws, size_t ws_size,
                              hipStream_t stream) {
  const float* obs = (const float*)d_in[0];
  const float* Wih = (const float*)d_in[1];
  const float* Whh = (const float*)d_in[2];
  const float* bih = (const float*)d_in[3];
  const float* bhh = (const float*)d_in[4];
  const float* W2 = (const float*)d_in[5];
  const float* b2 = (const float*)d_in[6];
  const float* Wm = (const float*)d_in[7];
  const float* bm = (const float*)d_in[8];
  const float* Ws = (const float*)d_in[9];
  const float* bs = (const float*)d_in[10];

  char* ws = (char*)d_ws;
  h2* whh = (h2*)(ws + 0);            // 512 KB
  h2* wih = (h2*)(ws + 524288);       // 128 KB
  h2* w2w = (h2*)(ws + 655360);       // 128 KB
  h2* wmh = (h2*)(ws + 786432);       // 16 KB
  float* bg = (float*)(ws + 802816);  // 4 KB

  prep_kernel<<<512, 256, 0, stream>>>(Wih, Whh, bih, bhh, W2, Wm, Ws,
                                       whh, wih, w2w, wmh, bg);
  actor_kernel<<<NB, NTHREADS, 0, stream>>>(obs, whh, wih, w2w, wmh, bg, b2, bm,
                                            bs, (float*)d_out);
}